// Round 11
// baseline (291.355 us; speedup 1.0000x reference)
//
#include <hip/hip_runtime.h>

typedef unsigned short u16;
typedef __bf16 bf16x8 __attribute__((ext_vector_type(8)));
typedef float f32x4 __attribute__((ext_vector_type(4)));

// ---------- sizes ----------
#define Bsz 8192
#define Fdim 1024
#define Udim 512
#define Odim 3
#define Adim 6
#define Hdim 4

// ws element offsets (u16 elements)
#define OFF_FEAT   0
#define OFF_WAL    8388608     // W_lat = [W_al ; W_ol] contiguous (2048 x 1024)
#define OFF_WIN    10485760
#define OFF_WOUT   11272192
#define OFF_WAH    11534336
#define OFF_WOH    12058624
#define OFF_LAT    12845056    // B x 2048 : [agent_latent | opp0 | opp1 | opp2]
#define OFF_Q      29622272    // B x 512
#define OFF_KV     33816576    // 3 x B x 1024 : [k | v]
#define OFF_OPH    67371008    // 3 x B x 512
#define OFF_WOUTT  79953920    // 512 x 512 bf16 : W_out^T
#define OFF_WCOMB  80216064    // 512 x 512 bf16 : W_ah[:,512:] @ W_out
#define OFF_BAHC   80478208    // 512 f32 : b_ah + W_ah[:,512:] @ b_out
#define OFF_ZB     80479232    // 512 f32 : zeros

// d_out offsets (fp32 elements)
#define OUT_AP 0
#define OUT_AV 49152
#define OUT_OP 57344
#define OUT_OV 204800
#define OUT_IN 229376

__device__ __forceinline__ u16 f2bf(float f) {
  return __builtin_bit_cast(u16, (__bf16)f);
}
__device__ __forceinline__ float bf2f(u16 u) {
  return (float)__builtin_bit_cast(__bf16, u);
}

__device__ __forceinline__ void gload16(const u16* g, u16* s) {
  __builtin_amdgcn_global_load_lds(
      (const __attribute__((address_space(1))) unsigned int*)g,
      (__attribute__((address_space(3))) unsigned int*)s, 16, 0, 0);
}

// ---------- fp32 -> bf16 conversion + prep (woutT transpose, bahc, zb) ------
#define CV_E0 2097152
#define CV_E1 2228224
#define CV_E2 2621440
#define CV_E3 2818048
#define CV_E4 2883584
#define CV_E5 3014656
#define CV_E6 3211264
__global__ __launch_bounds__(256) void convert_all(
    const float* __restrict__ f, const float* __restrict__ wal,
    const float* __restrict__ wol, const float* __restrict__ win,
    const float* __restrict__ wout, const float* __restrict__ wah,
    const float* __restrict__ woh, u16* __restrict__ dst,
    u16* __restrict__ woutT, float* __restrict__ bahc,
    const float* __restrict__ bout_f, const float* __restrict__ bah_f,
    float* __restrict__ zb) {
  if (blockIdx.x >= 12608) {
    // bahc: 64 blocks x 8 rows; wave handles 2 rows, lanes split the 512 dim
    const int wave = threadIdx.x >> 6, lane = threadIdx.x & 63;
    const int jbase = (blockIdx.x - 12608) * 8 + wave * 2;
#pragma unroll
    for (int t = 0; t < 2; ++t) {
      const int j = jbase + t;
      float s = 0.f;
#pragma unroll
      for (int c = 0; c < 8; ++c)
        s += wah[j * 1024 + 512 + c * 64 + lane] * bout_f[c * 64 + lane];
#pragma unroll
      for (int d = 32; d; d >>= 1) s += __shfl_xor(s, d, 64);
      if (lane == 0) bahc[j] = bah_f[j] + s;
    }
    return;
  }
  if (blockIdx.x >= 12544) {
    // transpose: woutT[u][v] = W_out[v][u]
    const int bid = blockIdx.x - 12544;
    if (bid == 0) {
      zb[threadIdx.x] = 0.f;
      zb[threadIdx.x + 256] = 0.f;
    }
    __shared__ float tile[64][65];
    const int bx = bid & 7, byy = bid >> 3;
    const int v0 = byy * 64, u0 = bx * 64;
#pragma unroll
    for (int it = 0; it < 16; ++it) {
      int idx = it * 256 + threadIdx.x;
      int r = idx >> 6, c = idx & 63;
      tile[r][c] = wout[(v0 + r) * 512 + u0 + c];
    }
    __syncthreads();
#pragma unroll
    for (int it = 0; it < 16; ++it) {
      int idx = it * 256 + threadIdx.x;
      int r = idx >> 6, c = idx & 63;
      woutT[(u0 + r) * 512 + v0 + c] = f2bf(tile[c][r]);
    }
    return;
  }
  int i = blockIdx.x * 256 + threadIdx.x;
  const float* src;
  int base;
  if (i < CV_E0)      { src = f;    base = 0; }
  else if (i < CV_E1) { src = wal;  base = CV_E0; }
  else if (i < CV_E2) { src = wol;  base = CV_E1; }
  else if (i < CV_E3) { src = win;  base = CV_E2; }
  else if (i < CV_E4) { src = wout; base = CV_E3; }
  else if (i < CV_E5) { src = wah;  base = CV_E4; }
  else                { src = woh;  base = CV_E5; }
  float4 v = ((const float4*)src)[i - base];
  ushort4 o;
  o.x = f2bf(v.x); o.y = f2bf(v.y); o.z = f2bf(v.z); o.w = f2bf(v.w);
  ((ushort4*)dst)[i] = o;
}

// ============================================================================
// 256x256 8-phase bf16 GEMM for lat = elu(feat @ W_lat^T + b). Unchanged from
// round 2 (verified: FETCH near-ideal, 0 bank conflicts).
// ============================================================================
#define BAR() __builtin_amdgcn_s_barrier()
#define FENCE() asm volatile("" ::: "memory")
#define LGKM0() asm volatile("s_waitcnt lgkmcnt(0)" ::: "memory")
#define VMW(n) asm volatile("s_waitcnt vmcnt(" #n ")" ::: "memory")
#define MFMA(a, b, c) __builtin_amdgcn_mfma_f32_16x16x32_bf16(a, b, c, 0, 0, 0)
#define STAGE(MAT, SRC, LD, buf, ks, kb) do {                    \
    const u16* _s = (SRC) + (size_t)(kb) + (ks) * 32;            \
    gload16(_s, &MAT[buf][ks][wave * 512]);                      \
    gload16(_s + (size_t)128 * (LD), &MAT[buf][ks][4096 + wave * 512]); \
  } while (0)
#define RD_A(cur, ks, mh) do {                                   \
    _Pragma("unroll")                                            \
    for (int mi = 0; mi < 4; mi++)                               \
      a0[mi] = *(const bf16x8*)&As[cur][ks][aoff + (mh)*2048 + mi*512]; \
  } while (0)
#define RD_B(cur, ks) do {                                       \
    _Pragma("unroll")                                            \
    for (int ni = 0; ni < 4; ni++)                               \
      b0[ni] = *(const bf16x8*)&Bs[cur][ks][boff + ni*512];      \
  } while (0)
#define MFMA8(mh) do {                                           \
    __builtin_amdgcn_s_setprio(1);                               \
    _Pragma("unroll")                                            \
    for (int mi = 0; mi < 4; mi++) {                             \
      _Pragma("unroll")                                          \
      for (int ni = 0; ni < 4; ni++)                             \
        acc[(mh)*4+mi][ni] = MFMA(a0[mi], b0[ni], acc[(mh)*4+mi][ni]); \
    }                                                            \
    __builtin_amdgcn_s_setprio(0);                               \
  } while (0)

template <bool ELU>
__global__ __launch_bounds__(512, 2) void gemm256(
    const u16* __restrict__ A, const u16* __restrict__ Bw, u16* __restrict__ C,
    const float* __restrict__ bias1, const float* __restrict__ bias2,
    int bsplit, int K, int lda, int ldb, int ldc,
    long sAz, long sBz, long sCz, int sbz, float scale) {
  __shared__ __align__(16) u16 As[2][2][8192];
  __shared__ __align__(16) u16 Bs[2][2][8192];
  const int tid = threadIdx.x;
  const int wave = tid >> 6, lane = tid & 63;
  const int wr = wave >> 2, wc = wave & 3;

  const int nx = gridDim.x, ny = gridDim.y;
  const int nxy = nx * ny;
  const int nwg = nxy * gridDim.z;
  const int orig = blockIdx.x + nx * (blockIdx.y + ny * blockIdx.z);
  const int xcd = orig & 7;
  const int qd = nwg >> 3, rd = nwg & 7;
  const int wg = (xcd < rd ? xcd * (qd + 1) : rd * (qd + 1) + (xcd - rd) * qd)
               + (orig >> 3);
  const int z = wg / nxy;
  const int rem = wg - z * nxy;
  const int by = rem / nx;
  const int bx = rem - by * nx;

  A += (size_t)z * sAz;
  Bw += (size_t)z * sBz;
  C += (size_t)z * sCz;
  bias1 += (size_t)z * sbz;

  const int tM = by * 256, tN = bx * 256;

  const int srow = tid >> 2;
  const int schunk = ((tid & 3) ^ ((tid >> 3) & 3)) * 8;
  const u16* Asrc = A + (size_t)(tM + srow) * lda + schunk;
  const u16* Bsrc = Bw + (size_t)(tN + srow) * ldb + schunk;

  const int laneLo = lane & 15;
  const int pc8 = (((lane >> 4) ^ ((lane >> 1) & 3))) * 8;
  const int aoff = (wr * 128 + laneLo) * 32 + pc8;
  const int boff = (wc * 64 + laneLo) * 32 + pc8;

  f32x4 acc[8][4];
#pragma unroll
  for (int mi = 0; mi < 8; mi++)
#pragma unroll
    for (int ni = 0; ni < 4; ni++) acc[mi][ni] = (f32x4){0.f, 0.f, 0.f, 0.f};

  const int NT = K >> 6;

  STAGE(As, Asrc, lda, 0, 0, 0);
  STAGE(Bs, Bsrc, ldb, 0, 0, 0);
  STAGE(As, Asrc, lda, 0, 1, 0);
  STAGE(Bs, Bsrc, ldb, 0, 1, 0);
  VMW(4);
  BAR();

  int cur = 0;
  int kb = 64;
  bf16x8 a0[4], b0[4];
  for (int t = 0; t < NT; ++t) {
    const int nxt = cur ^ 1;
    const bool st = (t + 1 < NT);
    RD_B(cur, 0);
    RD_A(cur, 0, 0);
    if (st) STAGE(As, Asrc, lda, nxt, 0, kb);
    FENCE(); BAR(); LGKM0();
    MFMA8(0);
    FENCE(); BAR();
    RD_A(cur, 0, 1);
    if (st) STAGE(Bs, Bsrc, ldb, nxt, 0, kb);
    FENCE(); BAR(); LGKM0();
    MFMA8(1);
    if (st) { VMW(4); } else { VMW(0); }
    BAR();
    RD_B(cur, 1);
    RD_A(cur, 1, 0);
    if (st) STAGE(As, Asrc, lda, nxt, 1, kb);
    FENCE(); BAR(); LGKM0();
    MFMA8(0);
    FENCE(); BAR();
    RD_A(cur, 1, 1);
    if (st) STAGE(Bs, Bsrc, ldb, nxt, 1, kb);
    FENCE(); BAR(); LGKM0();
    MFMA8(1);
    if (st) { VMW(4); BAR(); }
    cur = nxt;
    kb += 64;
  }

#pragma unroll
  for (int ni = 0; ni < 4; ni++) {
    const int col = tN + wc * 64 + ni * 16 + laneLo;
    const float bv = (col < bsplit) ? bias1[col] : bias2[col - bsplit];
#pragma unroll
    for (int gm = 0; gm < 8; gm++) {
      const int row0 = tM + wr * 128 + gm * 16 + (lane >> 4) * 4;
#pragma unroll
      for (int r = 0; r < 4; r++) {
        float v = (acc[gm][ni][r] + bv) * scale;
        if (ELU) v = v > 0.f ? v : (__expf(v) - 1.f);
        C[(size_t)(row0 + r) * ldc + col] = f2bf(v);
      }
    }
  }
}
#undef STAGE
#undef RD_A
#undef RD_B
#undef MFMA8

// ============================================================================
// mega: exact-grid (2576 blocks, 1D) z-routed launch for all post-lat GEMMs.
// Unchanged from r9 (verified, 70.5 us).
// ============================================================================
__global__ __launch_bounds__(256) void mega(
    const u16* __restrict__ lat, const u16* __restrict__ win,
    const u16* __restrict__ woh, const u16* __restrict__ wahb,
    const u16* __restrict__ woutT,
    u16* __restrict__ qb, u16* __restrict__ kvb, u16* __restrict__ oph,
    u16* __restrict__ wcomb,
    const float* __restrict__ b_in, const float* __restrict__ b_oh,
    const float* __restrict__ zb) {
  constexpr int BM = 128, BK = 32, BN = 128, NI = 4;
  __shared__ __align__(16) u16 As[BM * BK];
  __shared__ __align__(16) u16 Bs[BN * BK];
  const int wave = threadIdx.x >> 6, lane = threadIdx.x & 63;

  const int orig = blockIdx.x;
  const int wg = (orig & 7) * 322 + (orig >> 3);

  const u16 *A, *Bw;
  u16* C;
  const float* bias;
  int bx, by, ldc, lda = 2048;
  bool elu = false;
  float scale = 1.f;
  if (wg < 256) {
    bx = wg & 3; by = wg >> 2;
    A = lat; Bw = win; C = qb; bias = b_in;
    ldc = 512; scale = 0.08838834764831845f;
  } else if (wg < 1792) {
    int t = wg - 256, o = t >> 9, r = t & 511;
    bx = r & 7; by = r >> 3;
    A = lat + 512 * (o + 1); Bw = win + 262144;
    C = kvb + (size_t)o * 8388608; bias = b_in + 512;
    ldc = 1024;
  } else if (wg < 2560) {
    int t = wg - 1792, o = t >> 8, r = t & 255;
    bx = r & 3; by = r >> 2;
    A = lat + 512 * (o + 1); Bw = woh + (size_t)o * 262144;
    C = oph + (size_t)o * 4194304; bias = b_oh + o * 512;
    ldc = 512; elu = true;
  } else {
    int t = wg - 2560;
    bx = t & 3; by = t >> 2;
    A = wahb + 512; lda = 1024; Bw = woutT;
    C = wcomb; bias = zb;
    ldc = 512;
  }
  const int tM = by * BM, tN = bx * BN;
  const int wr = wave >> 1, wc = wave & 1;

  f32x4 acc[4][NI];
#pragma unroll
  for (int i = 0; i < 4; i++)
#pragma unroll
    for (int j = 0; j < NI; j++) acc[i][j] = (f32x4){0.f, 0.f, 0.f, 0.f};

  const int srow = lane >> 2;
  const int scol = (lane & 3) * 8;

  for (int k0 = 0; k0 < 512; k0 += BK) {
    __syncthreads();
#pragma unroll
    for (int i = 0; i < 2; ++i) {
      int r = wave * 32 + i * 16;
      gload16(A + (size_t)(tM + r + srow) * lda + k0 + scol, &As[r * BK]);
    }
#pragma unroll
    for (int i = 0; i < 2; ++i) {
      int r = (wave * 2 + i) * 16;
      gload16(Bw + (size_t)(tN + r + srow) * 512 + k0 + scol, &Bs[r * BK]);
    }
    __syncthreads();
    bf16x8 af[4], bfr[NI];
#pragma unroll
    for (int mi = 0; mi < 4; mi++)
      af[mi] = *(const bf16x8*)&As[(wr * 64 + mi * 16 + (lane & 15)) * BK + (lane >> 4) * 8];
#pragma unroll
    for (int ni = 0; ni < NI; ni++)
      bfr[ni] = *(const bf16x8*)&Bs[(wc * 64 + ni * 16 + (lane & 15)) * BK + (lane >> 4) * 8];
#pragma unroll
    for (int mi = 0; mi < 4; mi++)
#pragma unroll
      for (int ni = 0; ni < NI; ni++)
        acc[mi][ni] = __builtin_amdgcn_mfma_f32_16x16x32_bf16(af[mi], bfr[ni], acc[mi][ni], 0, 0, 0);
  }

#pragma unroll
  for (int ni = 0; ni < NI; ni++) {
    int col = tN + wc * 64 + ni * 16 + (lane & 15);
    float bv = bias[col];
#pragma unroll
    for (int mi = 0; mi < 4; mi++) {
      int row0 = tM + wr * 64 + mi * 16 + (lane >> 4) * 4;
#pragma unroll
      for (int r = 0; r < 4; r++) {
        float v = (acc[mi][ni][r] + bv) * scale;
        if (elu) v = v > 0.f ? v : (__expf(v) - 1.f);
        C[(size_t)(row0 + r) * ldc + col] = f2bf(v);
      }
    }
  }
}

// ============================================================================
// tail: fused attention + agent_head GEMM + all output heads.
// 256 blocks x 512 threads; block owns 32 batch rows.
//   phase A: stage AL = lat agent rows (swizzled, r5 pattern; loads overlap
//            with attn compute). attn per wave x 4 rows (r1 body verbatim),
//            att -> ATT in LDS (swizzled), influences written.
//   phase B: agh = elu([AL | ATT] @ [WahL ; Wcomb]^T + bahc): M=32 N=512
//            K=1024; B-slice (512x32) staged per K-step via gload16
//            (gemm_bt mechanics); A-frags read swizzled (r5 GEMM16 pattern).
//            agh stored back into AL (swizzled).
//   phase C: 28 length-512 dots per row: agent from swizzled AL (r6 DOTS),
//            opponents from global oph (r0 DOTS); weights read from
//            L2-resident fp32 globals (8-lane broadcast).
// Replaces attn_kernel + gemm_bt(agh) + heads_kernel: -2 launches, -2 gaps,
// att never round-trips to HBM.
// ============================================================================
__global__ __launch_bounds__(512) void tail(
    const u16* __restrict__ lat, const u16* __restrict__ qb,
    const u16* __restrict__ kvb, const u16* __restrict__ wahb,
    const u16* __restrict__ wcomb, const float* __restrict__ bahc,
    const u16* __restrict__ oph,
    const float* __restrict__ Wap, const float* __restrict__ bap,
    const float* __restrict__ Wav, const float* __restrict__ bav,
    const float* __restrict__ Wop, const float* __restrict__ bop,
    const float* __restrict__ Wov, const float* __restrict__ bov,
    float* __restrict__ out) {
  __shared__ __align__(16) u16 AL[16384];   // 32x512, swizzled; later agh
  __shared__ __align__(16) u16 ATT[16384];  // 32x512, swizzled
  __shared__ __align__(16) u16 Bs[16384];   // 512x32 weight K-slice
  const int tid = threadIdx.x;
  const int wave = tid >> 6, lane = tid & 63;
  const int row0 = blockIdx.x * 32;

  // ---- stage AL (agent latent rows, swizzled: slot s holds chunk s^(r&7)) ----
#pragma unroll
  for (int j = 0; j < 4; ++j) {
    int gq = j * 512 + tid;
    int r = gq >> 6, s = gq & 63, c = s ^ (r & 7);
    gload16(lat + (size_t)(row0 + r) * 2048 + c * 8, &AL[j * 4096 + wave * 512]);
  }

  // ---- attention: wave handles 4 rows (r1 body; att -> ATT swizzled) ----
  for (int t = 0; t < 4; ++t) {
    const int b = row0 + wave * 4 + t;
    const int rl = b - row0;
    const size_t qoff = (size_t)b * 512;
    float wacc0 = 0.f, wacc1 = 0.f, wacc2 = 0.f;
#pragma unroll
    for (int h = 0; h < 4; ++h) {
      const int off = h * 128 + lane * 2;
      ushort2 qu = *(const ushort2*)(qb + qoff + off);
      float qx = bf2f(qu.x), qy = bf2f(qu.y);
      float s[3];
#pragma unroll
      for (int o = 0; o < 3; ++o) {
        ushort2 ku = *(const ushort2*)(kvb + (size_t)o * (Bsz * 1024) + (size_t)b * 1024 + off);
        float p = qx * bf2f(ku.x) + qy * bf2f(ku.y);
#pragma unroll
        for (int d = 32; d; d >>= 1) p += __shfl_xor(p, d, 64);
        s[o] = p;
      }
      float m = fmaxf(s[0], fmaxf(s[1], s[2]));
      float e0 = __expf(s[0] - m), e1 = __expf(s[1] - m), e2 = __expf(s[2] - m);
      float inv = 1.f / (e0 + e1 + e2);
      float w0 = e0 * inv, w1 = e1 * inv, w2 = e2 * inv;
      wacc0 += w0; wacc1 += w1; wacc2 += w2;
      float ax = 0.f, ay = 0.f;
#pragma unroll
      for (int o = 0; o < 3; ++o) {
        float w = (o == 0) ? w0 : (o == 1) ? w1 : w2;
        ushort2 vu = *(const ushort2*)(kvb + (size_t)o * (Bsz * 1024) + (size_t)b * 1024 + 512 + off);
        ax += w * bf2f(vu.x);
        ay += w * bf2f(vu.y);
      }
      ushort2 st; st.x = f2bf(ax); st.y = f2bf(ay);
      const int col = off;                 // h*128 + lane*2
      const int slot = (col >> 3) ^ (rl & 7);
      *(ushort2*)(&ATT[rl * 512 + slot * 8 + (col & 7)]) = st;
    }
    if (lane == 0) {
      out[OUT_IN + (size_t)b * 3 + 0] = wacc0 * 0.25f;
      out[OUT_IN + (size_t)b * 3 + 1] = wacc1 * 0.25f;
      out[OUT_IN + (size_t)b * 3 + 2] = wacc2 * 0.25f;
    }
  }
  __syncthreads();   // ATT complete; AL gloads drained

  // ---- agh GEMM: M=32, N=512, K=1024 (A = [AL | ATT], B = [WahL ; Wcomb]) ----
  const int ll = lane & 15, lh = lane >> 4, l7 = lane & 7;
  const int wc0 = wave * 64;
  f32x4 acc[2][4];
#pragma unroll
  for (int mf = 0; mf < 2; ++mf)
#pragma unroll
    for (int nf = 0; nf < 4; ++nf) acc[mf][nf] = (f32x4){0.f, 0.f, 0.f, 0.f};

  for (int step = 0; step < 32; ++step) {
    const u16* bsrc;
    int ldb;
    if (step < 16) { bsrc = wahb + step * 32;          ldb = 1024; }
    else           { bsrc = wcomb + (step - 16) * 32;  ldb = 512; }
    __syncthreads();   // previous step's Bs readers done
#pragma unroll
    for (int j = 0; j < 4; ++j) {
      int id = j * 512 + tid;          // 2048 16B-chunks: row = id>>2, kc = id&3
      gload16(bsrc + (size_t)(id >> 2) * ldb + (id & 3) * 8,
              &Bs[j * 4096 + wave * 512]);
    }
    __syncthreads();   // Bs resident
    const u16* ABUF = (step < 16) ? AL : ATT;
    const int c9 = step & 15;
    bf16x8 a0 = *(const bf16x8*)&ABUF[ll * 512 + (((c9 * 4 + lh) ^ l7) * 8)];
    bf16x8 a1 = *(const bf16x8*)&ABUF[(16 + ll) * 512 + (((c9 * 4 + lh) ^ l7) * 8)];
#pragma unroll
    for (int nf = 0; nf < 4; ++nf) {
      bf16x8 bf = *(const bf16x8*)&Bs[(wc0 + nf * 16 + ll) * 32 + lh * 8];
      acc[0][nf] = __builtin_amdgcn_mfma_f32_16x16x32_bf16(a0, bf, acc[0][nf], 0, 0, 0);
      acc[1][nf] = __builtin_amdgcn_mfma_f32_16x16x32_bf16(a1, bf, acc[1][nf], 0, 0, 0);
    }
  }

  // epilogue: agh = elu(acc + bahc) -> AL (swizzled; AL reads long done)
#pragma unroll
  for (int nf = 0; nf < 4; ++nf) {
    const int col = wc0 + nf * 16 + ll;
    const float bb = bahc[col];
#pragma unroll
    for (int mf = 0; mf < 2; ++mf)
#pragma unroll
      for (int r = 0; r < 4; ++r) {
        const int row = mf * 16 + lh * 4 + r;
        float v = acc[mf][nf][r] + bb;
        v = v > 0.f ? v : (__expf(v) - 1.f);
        AL[row * 512 + (((col >> 3) ^ (row & 7)) * 8) + (col & 7)] = f2bf(v);
      }
  }
  __syncthreads();   // agh visible to all

  // ---- heads: waves 0-3, 8 rows each; kq = lane&7 owns a 64-elem slice ----
  if (wave < 4) {
    const int rl = wave * 8 + (lane >> 3), kq = lane & 7;
    const int b = row0 + rl;
    bf16x8 av[8];
    // agent segment: swizzled AL read (r6 DOTS pattern)
#pragma unroll
    for (int c = 0; c < 8; ++c)
      av[c] = *(const bf16x8*)&AL[rl * 512 + (((c * 8 + kq) ^ (rl & 7)) * 8)];
#pragma unroll
    for (int p = 0; p < 7; ++p) {
      const float* wg = (p < 6) ? Wap + p * 512 : Wav;
      float ac = 0.f;
#pragma unroll
      for (int c = 0; c < 8; ++c) {
        float4 w0 = *(const float4*)(wg + c * 64 + kq * 8);
        float4 w1 = *(const float4*)(wg + c * 64 + kq * 8 + 4);
        ac += (float)av[c][0] * w0.x + (float)av[c][1] * w0.y
            + (float)av[c][2] * w0.z + (float)av[c][3] * w0.w
            + (float)av[c][4] * w1.x + (float)av[c][5] * w1.y
            + (float)av[c][6] * w1.z + (float)av[c][7] * w1.w;
      }
      ac += __shfl_xor(ac, 1, 64);
      ac += __shfl_xor(ac, 2, 64);
      ac += __shfl_xor(ac, 4, 64);
      if (kq == p) {
        if (p < 6) out[OUT_AP + b * 6 + p] = ac + bap[p];
        else       out[OUT_AV + b] = ac + bav[0];
      }
    }
    // opponent segments: linear global oph (r0 DOTS pattern)
    for (int o = 0; o < 3; ++o) {
      const u16* src = oph + ((size_t)o * Bsz + b) * 512;
#pragma unroll
      for (int c = 0; c < 8; ++c)
        av[c] = *(const bf16x8*)(src + c * 64 + kq * 8);
#pragma unroll
      for (int p = 0; p < 7; ++p) {
        const float* wg = (p < 6) ? Wop + o * 3072 + p * 512 : Wov + o * 512;
        float ac = 0.f;
#pragma unroll
        for (int c = 0; c < 8; ++c) {
          float4 w0 = *(const float4*)(wg + c * 64 + kq * 8);
          float4 w1 = *(const float4*)(wg + c * 64 + kq * 8 + 4);
          ac += (float)av[c][0] * w0.x + (float)av[c][1] * w0.y
              + (float)av[c][2] * w0.z + (float)av[c][3] * w0.w
              + (float)av[c][4] * w1.x + (float)av[c][5] * w1.y
              + (float)av[c][6] * w1.z + (float)av[c][7] * w1.w;
        }
        ac += __shfl_xor(ac, 1, 64);
        ac += __shfl_xor(ac, 2, 64);
        ac += __shfl_xor(ac, 4, 64);
        if (kq == p) {
          if (p < 6) out[OUT_OP + b * 18 + o * 6 + p] = ac + bop[o * 6 + p];
          else       out[OUT_OV + b * 3 + o] = ac + bov[o];
        }
      }
    }
  }
}

extern "C" void kernel_launch(void* const* d_in, const int* in_sizes, int n_in,
                              void* d_out, int out_size, void* d_ws, size_t ws_size,
                              hipStream_t stream) {
  (void)in_sizes; (void)n_in; (void)out_size; (void)ws_size;
  const float* f     = (const float*)d_in[0];
  const float* W_al  = (const float*)d_in[1];
  const float* b_al  = (const float*)d_in[2];
  const float* W_in  = (const float*)d_in[3];
  const float* b_in  = (const float*)d_in[4];
  const float* W_out = (const float*)d_in[5];
  const float* b_out = (const float*)d_in[6];
  const float* W_ah  = (const float*)d_in[7];
  const float* b_ah  = (const float*)d_in[8];
  const float* W_ap  = (const float*)d_in[9];
  const float* b_ap  = (const float*)d_in[10];
  const float* W_av  = (const float*)d_in[11];
  const float* b_av  = (const float*)d_in[12];
  const float* W_ol  = (const float*)d_in[13];
  const float* b_ol  = (const float*)d_in[14];
  const float* W_oh  = (const float*)d_in[15];
  const float* b_oh  = (const float*)d_in[16];
  const float* W_op  = (const float*)d_in[17];
  const float* b_op  = (const float*)d_in[18];
  const float* W_ov  = (const float*)d_in[19];
  const float* b_ov  = (const float*)d_in[20];
  float* out = (float*)d_out;
  u16* ws = (u16*)d_ws;

  u16* feat  = ws + OFF_FEAT;
  u16* wal   = ws + OFF_WAL;    // [W_al ; W_ol] = W_lat (2048 x 1024)
  u16* win   = ws + OFF_WIN;
  u16* wahb  = ws + OFF_WAH;
  u16* woh   = ws + OFF_WOH;
  u16* lat   = ws + OFF_LAT;    // B x 2048
  u16* qbuf  = ws + OFF_Q;
  u16* kvb   = ws + OFF_KV;
  u16* oph   = ws + OFF_OPH;
  u16* woutT = ws + OFF_WOUTT;
  u16* wcomb = ws + OFF_WCOMB;
  float* bahc = (float*)(ws + OFF_BAHC);
  float* zb   = (float*)(ws + OFF_ZB);

  // convert + woutT transpose + bahc + zb : one launch
  convert_all<<<12672, 256, 0, stream>>>(f, W_al, W_ol, W_in, W_out, W_ah,
                                         W_oh, ws, woutT, bahc, b_out, b_ah,
                                         zb);

  // lat = elu(feat @ W_lat^T + [b_al|b_ol]) : B x 2048
  gemm256<true><<<dim3(8, 32, 1), 512, 0, stream>>>(
      feat, wal, lat, b_al, b_ol, 512, 1024, 1024, 1024, 2048, 0, 0, 0, 0, 1.f);

  // q, kv(x3), opp_heads(x3), Wcomb : one exact-grid launch
  mega<<<2576, 256, 0, stream>>>(
      lat, win, woh, wahb, woutT, qbuf, kvb, oph, wcomb, b_in, b_oh, zb);

  // attention + agent_head + all output heads : one fused launch
  tail<<<256, 512, 0, stream>>>(lat, qbuf, kvb, wahb, wcomb, bahc, oph,
                                W_ap, b_ap, W_av, b_av,
                                W_op, b_op, W_ov, b_ov, out);
}